// Round 1
// baseline (1179.066 us; speedup 1.0000x reference)
//
#include <hip/hip_runtime.h>

// NeuralCDE: B=256, T=1024, C=8, H=64, W=128.
// One block per batch element; 512 threads; 1023 sequential steps in-kernel.
// W2 (128x512 fp32) register-resident: 128 VGPR/thread across 512 threads.
// LDS: z[64], h[128], dx[2][8] only (<1KB). All LDS reads broadcast/2-way.

#define NB    256
#define TT    1024
#define NSTEP 1023
#define CC    8
#define HH    64
#define WW    128
#define KK    512   // H*C

typedef float v2f __attribute__((ext_vector_type(2)));

__device__ __forceinline__ float fast_tanh(float x) {
    // 1 - 2/(e^{2x}+1); saturates correctly for |x| large (inf -> 1, 0 -> -1)
    float e = __expf(2.0f * x);
    return 1.0f - 2.0f * __builtin_amdgcn_rcpf(e + 1.0f);
}

__global__ __launch_bounds__(512, 2)
void cde_kernel(const float* __restrict__ ca, const float* __restrict__ cb,
                const float* __restrict__ cc, const float* __restrict__ cd,
                const float* __restrict__ Wi, const float* __restrict__ bi,
                const float* __restrict__ W1, const float* __restrict__ b1,
                const float* __restrict__ W2, const float* __restrict__ b2,
                float* __restrict__ out)
{
    const int b = blockIdx.x;
    const int t = threadIdx.x;

    __shared__ __align__(16) float z_lds[HH];
    __shared__ __align__(16) float h_lds[WW];
    __shared__ __align__(16) float dx_lds[2][CC];

    // phase A mapping: quad (4 lanes) per output j; each lane 16 of 64 i's
    const int jA = t >> 2;      // 0..127
    const int gA = t & 3;       // i-chunk
    // phase B mapping: quad per 4 consecutive k; lane's j-chunk = gB
    const int kB4 = (t >> 2) << 2;  // base k of quad (= t & ~3)
    const int gB  = t & 3;          // j-chunk (32 j's each)

    // ---- weights into registers (one-time) ----
    v2f w1r[8];
#pragma unroll
    for (int q = 0; q < 8; ++q) {
        int i0 = gA * 16 + 2 * q;
        v2f w = { W1[i0 * WW + jA], W1[(i0 + 1) * WW + jA] };
        w1r[q] = w;
    }
    const float b1r = b1[jA];

    v2f w2r[32][2];   // 128 VGPRs: W2[gB*32+jj][kB4..kB4+3]
#pragma unroll
    for (int jj = 0; jj < 32; ++jj) {
        int j = gB * 32 + jj;
        const float4 w4 = *reinterpret_cast<const float4*>(&W2[j * KK + kB4]);
        v2f a = { w4.x, w4.y };
        v2f c = { w4.z, w4.w };
        w2r[jj][0] = a;
        w2r[jj][1] = c;
    }
    const float b2r = b2[t];   // this lane's k == t

    // ---- z0 = a0 @ W_init + b_init ----
    if (t < HH) {
        float acc = bi[t];
#pragma unroll
        for (int c = 0; c < CC; ++c)
            acc = fmaf(ca[(size_t)b * NSTEP * CC + c], Wi[c * HH + t], acc);
        z_lds[t] = acc;
        out[((size_t)b * TT + 0) * HH + t] = acc;
    }
    if (t < CC) {
        size_t idx = ((size_t)b * NSTEP + 0) * CC + t;
        dx_lds[0][t] = cb[idx] + cc[idx] + 0.75f * cd[idx];
    }
    __syncthreads();

    const float4* z4 = reinterpret_cast<const float4*>(z_lds);
    const float4* h4 = reinterpret_cast<const float4*>(h_lds);

    for (int s = 0; s < NSTEP; ++s) {
        // ================= phase A: h = relu(z @ W1 + b1) =================
        // prefetch next step's dx early (hidden under compute)
        float nb = 0.f, nc = 0.f, nd = 0.f;
        const bool pref = (t < CC) && (s + 1 < NSTEP);
        if (pref) {
            size_t idx = ((size_t)b * NSTEP + (s + 1)) * CC + t;
            nb = cb[idx]; nc = cc[idx]; nd = cd[idx];
        }

        v2f p2 = { 0.f, 0.f };
#pragma unroll
        for (int q4 = 0; q4 < 4; ++q4) {
            float4 zq = z4[gA * 4 + q4];
            v2f zlo = { zq.x, zq.y };
            v2f zhi = { zq.z, zq.w };
            p2 = __builtin_elementwise_fma(zlo, w1r[2 * q4 + 0], p2);
            p2 = __builtin_elementwise_fma(zhi, w1r[2 * q4 + 1], p2);
        }
        float p = p2.x + p2.y;
        p += __shfl_xor(p, 1);
        p += __shfl_xor(p, 2);
        if (gA == 0) h_lds[jA] = fmaxf(p + b1r, 0.0f);
        if (pref) dx_lds[(s + 1) & 1][t] = nb + nc + 0.75f * nd;
        __syncthreads();

        // ============ phase B: f = tanh(h @ W2 + b2); z += f @ dx ============
        v2f o01 = { 0.f, 0.f }, o23 = { 0.f, 0.f };
#pragma unroll
        for (int ch = 0; ch < 8; ++ch) {
            float4 hv = h4[gB * 8 + ch];   // broadcast read (free)
            {
                v2f hs = { hv.x, hv.x };
                o01 = __builtin_elementwise_fma(hs, w2r[ch * 4 + 0][0], o01);
                o23 = __builtin_elementwise_fma(hs, w2r[ch * 4 + 0][1], o23);
            }
            {
                v2f hs = { hv.y, hv.y };
                o01 = __builtin_elementwise_fma(hs, w2r[ch * 4 + 1][0], o01);
                o23 = __builtin_elementwise_fma(hs, w2r[ch * 4 + 1][1], o23);
            }
            {
                v2f hs = { hv.z, hv.z };
                o01 = __builtin_elementwise_fma(hs, w2r[ch * 4 + 2][0], o01);
                o23 = __builtin_elementwise_fma(hs, w2r[ch * 4 + 2][1], o23);
            }
            {
                v2f hs = { hv.w, hv.w };
                o01 = __builtin_elementwise_fma(hs, w2r[ch * 4 + 3][0], o01);
                o23 = __builtin_elementwise_fma(hs, w2r[ch * 4 + 3][1], o23);
            }
        }
        // reduce the 4 j-chunk partials across the quad (butterfly -> all lanes)
        o01.x += __shfl_xor(o01.x, 1); o01.x += __shfl_xor(o01.x, 2);
        o01.y += __shfl_xor(o01.y, 1); o01.y += __shfl_xor(o01.y, 2);
        o23.x += __shfl_xor(o23.x, 1); o23.x += __shfl_xor(o23.x, 2);
        o23.y += __shfl_xor(o23.y, 1); o23.y += __shfl_xor(o23.y, 2);
        // each lane takes k == t
        float ok = (gB & 2) ? ((gB & 1) ? o23.y : o23.x)
                            : ((gB & 1) ? o01.y : o01.x);
        float f  = fast_tanh(ok + b2r);
        // z[h] += sum_c f[h*8+c] * dx[c]; k = t, c = t&7, h = t>>3
        float val = f * dx_lds[s & 1][t & 7];
        val += __shfl_xor(val, 1);
        val += __shfl_xor(val, 2);
        val += __shfl_xor(val, 4);
        if ((t & 7) == 0) {
            int h = t >> 3;
            float zn = z_lds[h] + val;
            z_lds[h] = zn;
            out[((size_t)b * TT + (s + 1)) * HH + h] = zn;
        }
        __syncthreads();
    }
}

extern "C" void kernel_launch(void* const* d_in, const int* in_sizes, int n_in,
                              void* d_out, int out_size, void* d_ws, size_t ws_size,
                              hipStream_t stream) {
    const float* ca = (const float*)d_in[0];
    const float* cb = (const float*)d_in[1];
    const float* cc = (const float*)d_in[2];
    const float* cd = (const float*)d_in[3];
    const float* Wi = (const float*)d_in[4];
    const float* bi = (const float*)d_in[5];
    const float* W1 = (const float*)d_in[6];
    const float* b1 = (const float*)d_in[7];
    const float* W2 = (const float*)d_in[8];
    const float* b2 = (const float*)d_in[9];
    float* out = (float*)d_out;

    hipLaunchKernelGGL(cde_kernel, dim3(NB), dim3(512), 0, stream,
                       ca, cb, cc, cd, Wi, bi, W1, b1, W2, b2, out);
}

// Round 3
// 993.091 us; speedup vs baseline: 1.1873x; 1.1873x over previous
//
#include <hip/hip_runtime.h>

// NeuralCDE: B=256, T=1024, C=8, H=64, W=128.
// One block per batch element (256 blocks = 256 CUs); 512 threads; 1023
// sequential steps in-kernel. W2 column k=t register-resident per thread
// (128 VGPRs), pinned with asm to defeat rematerialization. dx preloaded
// to LDS; step loop has no global loads. All LDS reads broadcast/2-way.

#define NB    256
#define TT    1024
#define NSTEP 1023
#define CC    8
#define HH    64
#define WW    128
#define KK    512   // H*C

typedef float v2f __attribute__((ext_vector_type(2)));

__device__ __forceinline__ float fast_tanh(float x) {
    // 1 - 2/(e^{2x}+1); saturates correctly (x->+inf: 1, x->-inf: -1)
    float e = __expf(2.0f * x);
    return 1.0f - 2.0f * __builtin_amdgcn_rcpf(e + 1.0f);
}

__global__ __launch_bounds__(512, 2)
void cde_kernel(const float* __restrict__ ca, const float* __restrict__ cb,
                const float* __restrict__ cc, const float* __restrict__ cd,
                const float* __restrict__ Wi, const float* __restrict__ bi,
                const float* __restrict__ W1, const float* __restrict__ b1,
                const float* __restrict__ W2, const float* __restrict__ b2,
                float* __restrict__ out)
{
    const int b = blockIdx.x;
    const int t = threadIdx.x;

    __shared__ __align__(16) float z_lds[HH];
    __shared__ __align__(16) float h_lds[WW];
    __shared__ __align__(16) float dx_all[NSTEP * CC];   // 32736 B

    // ---- W2 column k=t into registers: w2c[m] = {W2[2m][t], W2[2m+1][t]} ----
    // Column load is coalesced across the block (fixed row i -> threads read
    // consecutive addresses). One-time cost.
    v2f w2c[64];
#pragma unroll
    for (int m = 0; m < 64; ++m) {
        v2f w = { W2[(2 * m) * KK + t], W2[(2 * m + 1) * KK + t] };
        w2c[m] = w;
    }
    // Pin: asm is now the def of each value -> compiler cannot re-sink the
    // global loads into the step loop (round-1 failure mode: VGPR_Count=96).
#pragma unroll
    for (int m = 0; m < 64; ++m) asm volatile("" : "+v"(w2c[m]));
    const float b2r = b2[t];

    // ---- W1 (phase A): lane-quad per output jA, 16-element i-chunks ----
    const int jA = t >> 2;      // 0..127
    const int gA = t & 3;       // i-chunk
    v2f w1r[8];
#pragma unroll
    for (int q = 0; q < 8; ++q) {
        int i0 = gA * 16 + 2 * q;
        v2f w = { W1[i0 * WW + jA], W1[(i0 + 1) * WW + jA] };
        w1r[q] = w;
    }
#pragma unroll
    for (int q = 0; q < 8; ++q) asm volatile("" : "+v"(w1r[q]));
    const float b1r = b1[jA];

    // ---- preload dx for ALL steps into LDS (coalesced, one-time) ----
    {
        const size_t base = (size_t)b * NSTEP * CC;
        for (int i = t; i < NSTEP * CC; i += 512)
            dx_all[i] = cb[base + i] + cc[base + i] + 0.75f * cd[base + i];
    }

    // ---- z0 = a0 @ W_init + b_init ----
    if (t < HH) {
        float acc = bi[t];
#pragma unroll
        for (int c = 0; c < CC; ++c)
            acc = fmaf(ca[(size_t)b * NSTEP * CC + c], Wi[c * HH + t], acc);
        z_lds[t] = acc;
        out[((size_t)b * TT) * HH + t] = acc;
    }
    __syncthreads();

    const float4* z4 = reinterpret_cast<const float4*>(z_lds);
    const float4* h4 = reinterpret_cast<const float4*>(h_lds);

#pragma unroll 1
    for (int s = 0; s < NSTEP; ++s) {
        // ============ phase A: h = relu(z @ W1 + b1) ============
        // z4 reads: 2 addresses per bank-group across the wave = free (m136).
        v2f pa = { 0.f, 0.f }, pb = { 0.f, 0.f };
#pragma unroll
        for (int q4 = 0; q4 < 4; ++q4) {
            float4 zq = z4[gA * 4 + q4];
            v2f zlo = { zq.x, zq.y };
            v2f zhi = { zq.z, zq.w };
            pa = __builtin_elementwise_fma(zlo, w1r[2 * q4 + 0], pa);
            pb = __builtin_elementwise_fma(zhi, w1r[2 * q4 + 1], pb);
        }
        v2f ps = pa + pb;
        float p = ps.x + ps.y;
        p += __shfl_xor(p, 1);
        p += __shfl_xor(p, 2);
        if (gA == 0) h_lds[jA] = fmaxf(p + b1r, 0.0f);
        __syncthreads();

        // ===== phase B: o[k=t] = h . W2[:,t]; f=tanh(o+b2); z += f@dx =====
        // h reads are whole-wave broadcasts (same address) -> conflict-free.
        v2f o0 = {0,0}, o1 = {0,0}, o2 = {0,0}, o3 = {0,0};
#pragma unroll
        for (int q = 0; q < 8; ++q) {
            float4 ha = h4[4 * q + 0];
            float4 hb = h4[4 * q + 1];
            float4 hc = h4[4 * q + 2];
            float4 hd = h4[4 * q + 3];
            v2f a0 = { ha.x, ha.y }, a1 = { ha.z, ha.w };
            v2f b0 = { hb.x, hb.y }, b1v = { hb.z, hb.w };
            v2f c0 = { hc.x, hc.y }, c1 = { hc.z, hc.w };
            v2f d0 = { hd.x, hd.y }, d1 = { hd.z, hd.w };
            o0 = __builtin_elementwise_fma(a0,  w2c[8 * q + 0], o0);
            o1 = __builtin_elementwise_fma(a1,  w2c[8 * q + 1], o1);
            o2 = __builtin_elementwise_fma(b0,  w2c[8 * q + 2], o2);
            o3 = __builtin_elementwise_fma(b1v, w2c[8 * q + 3], o3);
            o0 = __builtin_elementwise_fma(c0,  w2c[8 * q + 4], o0);
            o1 = __builtin_elementwise_fma(c1,  w2c[8 * q + 5], o1);
            o2 = __builtin_elementwise_fma(d0,  w2c[8 * q + 6], o2);
            o3 = __builtin_elementwise_fma(d1,  w2c[8 * q + 7], o3);
        }
        v2f oo = (o0 + o1) + (o2 + o3);
        float ok = oo.x + oo.y;
        float f  = fast_tanh(ok + b2r);

        // z[h] += sum_c f[h*8+c] * dx[c];  k=t, c=t&7, h=t>>3
        float val = f * dx_all[s * CC + (t & 7)];
        val += __shfl_xor(val, 1);
        val += __shfl_xor(val, 2);
        val += __shfl_xor(val, 4);
        if ((t & 7) == 0) {
            int h = t >> 3;
            float zn = z_lds[h] + val;
            z_lds[h] = zn;
            out[((size_t)b * TT + (s + 1)) * HH + h] = zn;
        }
        __syncthreads();
    }
}

extern "C" void kernel_launch(void* const* d_in, const int* in_sizes, int n_in,
                              void* d_out, int out_size, void* d_ws, size_t ws_size,
                              hipStream_t stream) {
    const float* ca = (const float*)d_in[0];
    const float* cb = (const float*)d_in[1];
    const float* cc = (const float*)d_in[2];
    const float* cd = (const float*)d_in[3];
    const float* Wi = (const float*)d_in[4];
    const float* bi = (const float*)d_in[5];
    const float* W1 = (const float*)d_in[6];
    const float* b1 = (const float*)d_in[7];
    const float* W2 = (const float*)d_in[8];
    const float* b2 = (const float*)d_in[9];
    float* out = (float*)d_out;

    hipLaunchKernelGGL(cde_kernel, dim3(NB), dim3(512), 0, stream,
                       ca, cb, cc, cd, Wi, bi, W1, b1, W2, b2, out);
}

// Round 5
// 826.658 us; speedup vs baseline: 1.4263x; 1.2013x over previous
//
#include <hip/hip_runtime.h>

// NeuralCDE: B=256, T=1024, C=8, H=64, W=128.
// One block per batch element; 512 threads; 1023 sequential steps in-kernel.
// Round-4: phase B splits the 128-deep contraction across each lane-quad
// (i-chunks of 32) so each lane reads only 128B of h per step (vs 512B in
// round 3 -> LDS-return-BW bound at 2330 cy/step). Padded h layout kills the
// round-1 4-way bank conflict; quad reductions use DPP (VALU pipe), not the
// LDS pipe. W2 stays register/AGPR-resident via asm pin; dx preloaded to LDS.

#define NB    256
#define TT    1024
#define NSTEP 1023
#define CC    8
#define HH    64
#define WW    128
#define KK    512   // H*C

typedef float v2f __attribute__((ext_vector_type(2)));

__device__ __forceinline__ float fast_tanh(float x) {
    // 1 - 2/(e^{2x}+1); saturates correctly (x->+inf: 1, x->-inf: -1)
    float e = __expf(2.0f * x);
    return 1.0f - 2.0f * __builtin_amdgcn_rcpf(e + 1.0f);
}

// quad butterfly adds on the VALU pipe (DPP quad_perm), not LDS swizzles
__device__ __forceinline__ float qadd1(float x) {   // x += lane^1
    int yi = __builtin_amdgcn_mov_dpp(__builtin_bit_cast(int, x),
                                      0xB1, 0xF, 0xF, true); // [1,0,3,2]
    return x + __builtin_bit_cast(float, yi);
}
__device__ __forceinline__ float qadd2(float x) {   // x += lane^2
    int yi = __builtin_amdgcn_mov_dpp(__builtin_bit_cast(int, x),
                                      0x4E, 0xF, 0xF, true); // [2,3,0,1]
    return x + __builtin_bit_cast(float, yi);
}

__global__ __launch_bounds__(512, 2)
void cde_kernel(const float* __restrict__ ca, const float* __restrict__ cb,
                const float* __restrict__ cc, const float* __restrict__ cd,
                const float* __restrict__ Wi, const float* __restrict__ bi,
                const float* __restrict__ W1, const float* __restrict__ b1,
                const float* __restrict__ W2, const float* __restrict__ b2,
                float* __restrict__ out)
{
    const int b = blockIdx.x;
    const int t = threadIdx.x;

    __shared__ __align__(16) float z_lds[HH];
    __shared__ __align__(16) float h_pad[4][36];        // 144B rows: distinct banks per chunk
    __shared__ __align__(16) float dx_all[NSTEP * CC];  // 32736 B

    // ---- phase-B mapping: quad shares k-quad kb..kb+3, splits i by gB ----
    const int gB = t & 3;        // i-chunk: i in [32*gB, 32*gB+32)
    const int kb = t & ~3;       // k base of this quad (4*(t>>2))

    // ---- W2 fragment into registers: v2f pairs over i ----
    // w2a[ch][kk] = {W2[i0][kb+kk], W2[i0+1][kb+kk]}, i0 = 32*gB + 4*ch
    // w2b[ch][kk] = {W2[i0+2][kb+kk], W2[i0+3][kb+kk]}
    v2f w2a[8][4], w2b[8][4];   // 128 floats
#pragma unroll
    for (int ch = 0; ch < 8; ++ch) {
        int i0 = 32 * gB + 4 * ch;
#pragma unroll
        for (int kk = 0; kk < 4; ++kk) {
            v2f a = { W2[(i0 + 0) * KK + kb + kk], W2[(i0 + 1) * KK + kb + kk] };
            v2f c = { W2[(i0 + 2) * KK + kb + kk], W2[(i0 + 3) * KK + kb + kk] };
            w2a[ch][kk] = a;
            w2b[ch][kk] = c;
        }
    }
    // Pin: asm becomes the def -> loads cannot be re-sunk into the step loop.
#pragma unroll
    for (int ch = 0; ch < 8; ++ch)
#pragma unroll
        for (int kk = 0; kk < 4; ++kk) {
            asm volatile("" : "+v"(w2a[ch][kk]));
            asm volatile("" : "+v"(w2b[ch][kk]));
        }
    const float b2r = b2[t];     // quad butterfly returns ownership k == t

    // ---- W1 (phase A): lane-quad per output jA, 16-element i-chunks ----
    const int jA = t >> 2;      // 0..127
    const int gA = t & 3;       // i-chunk
    v2f w1r[8];
#pragma unroll
    for (int q = 0; q < 8; ++q) {
        int i0 = gA * 16 + 2 * q;
        v2f w = { W1[i0 * WW + jA], W1[(i0 + 1) * WW + jA] };
        w1r[q] = w;
    }
#pragma unroll
    for (int q = 0; q < 8; ++q) asm volatile("" : "+v"(w1r[q]));
    const float b1r = b1[jA];

    // ---- preload dx for ALL steps into LDS (coalesced, one-time) ----
    {
        const size_t base = (size_t)b * NSTEP * CC;
        for (int i = t; i < NSTEP * CC; i += 512)
            dx_all[i] = cb[base + i] + cc[base + i] + 0.75f * cd[base + i];
    }

    // ---- z0 = a0 @ W_init + b_init ----
    if (t < HH) {
        float acc = bi[t];
#pragma unroll
        for (int c = 0; c < CC; ++c)
            acc = fmaf(ca[(size_t)b * NSTEP * CC + c], Wi[c * HH + t], acc);
        z_lds[t] = acc;
        out[((size_t)b * TT) * HH + t] = acc;
    }
    __syncthreads();

    const float4* z4 = reinterpret_cast<const float4*>(z_lds);

#pragma unroll 1
    for (int s = 0; s < NSTEP; ++s) {
        // ============ phase A: h = relu(z @ W1 + b1) ============
        v2f pa = { 0.f, 0.f }, pb = { 0.f, 0.f };
#pragma unroll
        for (int q4 = 0; q4 < 4; ++q4) {
            float4 zq = z4[gA * 4 + q4];
            v2f zlo = { zq.x, zq.y };
            v2f zhi = { zq.z, zq.w };
            pa = __builtin_elementwise_fma(zlo, w1r[2 * q4 + 0], pa);
            pb = __builtin_elementwise_fma(zhi, w1r[2 * q4 + 1], pb);
        }
        v2f ps = pa + pb;
        float p = ps.x + ps.y;
        p = qadd1(p);
        p = qadd2(p);
        if (gA == 0) h_pad[jA >> 5][jA & 31] = fmaxf(p + b1r, 0.0f);
        __syncthreads();

        // ===== phase B: o[k] = h . W2[:,k] (quad i-split); f=tanh; z += f@dx =====
        // lane reads only its 32-h chunk: 8 x ds_read_b128, conflict-free (padded rows)
        const float4* hp = reinterpret_cast<const float4*>(&h_pad[gB][0]);
        v2f a0 = {0,0}, a1 = {0,0}, a2 = {0,0}, a3 = {0,0};
#pragma unroll
        for (int ch = 0; ch < 8; ++ch) {
            float4 hv = hp[ch];
            v2f h01 = { hv.x, hv.y };   // register-pair aliases, no dup movs
            v2f h23 = { hv.z, hv.w };
            a0 = __builtin_elementwise_fma(h01, w2a[ch][0], a0);
            a1 = __builtin_elementwise_fma(h01, w2a[ch][1], a1);
            a2 = __builtin_elementwise_fma(h01, w2a[ch][2], a2);
            a3 = __builtin_elementwise_fma(h01, w2a[ch][3], a3);
            a0 = __builtin_elementwise_fma(h23, w2b[ch][0], a0);
            a1 = __builtin_elementwise_fma(h23, w2b[ch][1], a1);
            a2 = __builtin_elementwise_fma(h23, w2b[ch][2], a2);
            a3 = __builtin_elementwise_fma(h23, w2b[ch][3], a3);
        }
        float o0 = a0.x + a0.y;
        float o1 = a1.x + a1.y;
        float o2 = a2.x + a2.y;
        float o3 = a3.x + a3.y;
        // quad butterfly (DPP): sum the 4 i-chunk partials; all lanes get totals
        o0 = qadd2(qadd1(o0));
        o1 = qadd2(qadd1(o1));
        o2 = qadd2(qadd1(o2));
        o3 = qadd2(qadd1(o3));
        // lane takes k = kb + gB == t
        float ok = (gB & 2) ? ((gB & 1) ? o3 : o2)
                            : ((gB & 1) ? o1 : o0);
        float f  = fast_tanh(ok + b2r);

        // z[h] += sum_c f[h*8+c] * dx[c];  k=t, c=t&7, h=t>>3
        float val = f * dx_all[s * CC + (t & 7)];
        val = qadd1(val);
        val = qadd2(val);
        val += __shfl_xor(val, 4);
        if ((t & 7) == 0) {
            int h = t >> 3;
            float zn = z_lds[h] + val;
            z_lds[h] = zn;
            out[((size_t)b * TT + (s + 1)) * HH + h] = zn;
        }
        __syncthreads();
    }
}

extern "C" void kernel_launch(void* const* d_in, const int* in_sizes, int n_in,
                              void* d_out, int out_size, void* d_ws, size_t ws_size,
                              hipStream_t stream) {
    const float* ca = (const float*)d_in[0];
    const float* cb = (const float*)d_in[1];
    const float* cc = (const float*)d_in[2];
    const float* cd = (const float*)d_in[3];
    const float* Wi = (const float*)d_in[4];
    const float* bi = (const float*)d_in[5];
    const float* W1 = (const float*)d_in[6];
    const float* b1 = (const float*)d_in[7];
    const float* W2 = (const float*)d_in[8];
    const float* b2 = (const float*)d_in[9];
    float* out = (float*)d_out;

    hipLaunchKernelGGL(cde_kernel, dim3(NB), dim3(512), 0, stream,
                       ca, cb, cc, cd, Wi, bi, W1, b1, W2, b2, out);
}